// Round 1
// baseline (109.930 us; speedup 1.0000x reference)
//
#include <hip/hip_runtime.h>
#include <math.h>

#define BB 64
#define NN 2048
#define DD 128
#define KD 16
#define NORMF 0.25f
#define CHUNK 32
#define CH (NN / CHUNK)   // 64 chunks per batch

// ---------------- zero kernel: clear d_out and the per-(b,branch) softmax sums
__global__ void zero_kernel(float* __restrict__ out, float* __restrict__ s_ws) {
    int idx = blockIdx.x * blockDim.x + threadIdx.x;
    if (idx < 2 * BB * DD) out[idx] = 0.0f;
    if (idx < 2 * BB) s_ws[idx] = 0.0f;
}

// ---------------- main kernel: one wave per (b, 32-row chunk)
__launch_bounds__(64)
__global__ void attn_partial(const float* __restrict__ h,
                             const float* __restrict__ adj,
                             const int*   __restrict__ phone,
                             const float* __restrict__ Wq_bf, const float* __restrict__ Wk_bf,
                             const float* __restrict__ Wv_bf, const float* __restrict__ Wo_bf,
                             const float* __restrict__ Wq_af, const float* __restrict__ Wk_af,
                             const float* __restrict__ Wv_af, const float* __restrict__ Wo_af,
                             float* __restrict__ out, float* __restrict__ s_ws)
{
    const int blk  = blockIdx.x;
    const int b    = blk / CH;
    const int ch   = blk % CH;
    const int lane = threadIdx.x;
    const int ph   = phone[b];

    __shared__ float hp_s[DD];        // h_phone
    __shared__ float q_s[2][KD];      // Q per branch
    __shared__ float hagg_s[2][DD];   // partial sum_n e*adj*h
    __shared__ float head_s[2][KD];   // partial head

    const float* hb = h + (size_t)b * NN * DD;

    // ---- h_phone -> LDS
    {
        float2 v = *(const float2*)(hb + (size_t)ph * DD + 2 * lane);
        hp_s[2 * lane]     = v.x;
        hp_s[2 * lane + 1] = v.y;
    }
    __syncthreads();

    // ---- Q[br][k] = sum_d h_phone[d] * Wq[d,k]   (lanes 0..31: br=lane>>4, k=lane&15)
    if (lane < 32) {
        int br = lane >> 4, k = lane & 15;
        const float* Wq = br ? Wq_af : Wq_bf;
        float q = 0.0f;
        #pragma unroll 4
        for (int d = 0; d < DD; ++d) q += hp_s[d] * Wq[d * KD + k];
        q_s[br][k] = q;
    }
    __syncthreads();

    // ---- per-lane key-projection vector w[d] = NORM * sum_k Wk[d,k]*Q[k], d = 4*(lane&31)+i
    const int dbase = 4 * (lane & 31);
    float wbf[4], waf[4];
    #pragma unroll
    for (int i = 0; i < 4; ++i) {
        float a = 0.0f, c = 0.0f;
        #pragma unroll
        for (int k = 0; k < KD; ++k) {
            a += Wk_bf[(dbase + i) * KD + k] * q_s[0][k];
            c += Wk_af[(dbase + i) * KD + k] * q_s[1][k];
        }
        wbf[i] = NORMF * a;
        waf[i] = NORMF * c;
    }

    // ---- adjacency values for this chunk (lane r < CHUNK holds row r)
    const int n0 = ch * CHUNK;
    float adjv = 0.0f;
    if (lane < CHUNK) adjv = adj[((size_t)b * NN + ph) * NN + n0 + lane];

    const int half = lane >> 5;   // lanes 0-31: even rows, 32-63: odd rows
    float s_bf = 0.0f, s_af = 0.0f;
    float hg_bf[4] = {0, 0, 0, 0}, hg_af[4] = {0, 0, 0, 0};

    for (int t = 0; t < CHUNK / 2; ++t) {
        const int r = 2 * t + half;
        const int n = n0 + r;
        float4 hv = *(const float4*)(hb + (size_t)n * DD + dbase);

        const bool af = (n >= ph);
        float w0 = af ? waf[0] : wbf[0];
        float w1 = af ? waf[1] : wbf[1];
        float w2 = af ? waf[2] : wbf[2];
        float w3 = af ? waf[3] : wbf[3];

        float p = hv.x * w0 + hv.y * w1 + hv.z * w2 + hv.w * w3;
        // reduce across the 32-lane half (xor masks < 32 stay within halves)
        #pragma unroll
        for (int m = 1; m <= 16; m <<= 1) p += __shfl_xor(p, m, 64);

        float compat = 10.0f * tanhf(p);
        float e = __expf(compat - 10.0f);       // fixed max: compat in (-10,10)
        float adjr = __shfl(adjv, r, 64);
        float es = (adjr != 0.0f) ? e : 0.0f;   // valid = in-branch (by construction) & adj!=0
        float ea = es * adjr;

        if (af) {
            s_af += es;
            hg_af[0] += ea * hv.x; hg_af[1] += ea * hv.y;
            hg_af[2] += ea * hv.z; hg_af[3] += ea * hv.w;
        } else {
            s_bf += es;
            hg_bf[0] += ea * hv.x; hg_bf[1] += ea * hv.y;
            hg_bf[2] += ea * hv.z; hg_bf[3] += ea * hv.w;
        }
    }

    // ---- combine the two halves (they own the same d-range, different rows)
    s_bf += __shfl_xor(s_bf, 32, 64);
    s_af += __shfl_xor(s_af, 32, 64);
    #pragma unroll
    for (int i = 0; i < 4; ++i) {
        hg_bf[i] += __shfl_xor(hg_bf[i], 32, 64);
        hg_af[i] += __shfl_xor(hg_af[i], 32, 64);
    }

    if (lane < 32) {
        #pragma unroll
        for (int i = 0; i < 4; ++i) {
            hagg_s[0][dbase + i] = hg_bf[i];
            hagg_s[1][dbase + i] = hg_af[i];
        }
    }
    if (lane == 0) {
        atomicAdd(&s_ws[b * 2 + 0], s_bf);
        atomicAdd(&s_ws[b * 2 + 1], s_af);
    }
    __syncthreads();

    // ---- project partial hagg through Wv (128->16)
    if (lane < 32) {
        int br = lane >> 4, k = lane & 15;
        const float* Wv = br ? Wv_af : Wv_bf;
        float hd = 0.0f;
        #pragma unroll 4
        for (int d = 0; d < DD; ++d) hd += hagg_s[br][d] * Wv[d * KD + k];
        head_s[br][k] = hd;
    }
    __syncthreads();

    // ---- project through Wo (16->128) and atomically accumulate raw output
    #pragma unroll
    for (int br = 0; br < 2; ++br) {
        const float* Wo = br ? Wo_af : Wo_bf;
        float o0 = 0.0f, o1 = 0.0f;
        #pragma unroll
        for (int k = 0; k < KD; ++k) {
            o0 += head_s[br][k] * Wo[k * DD + lane];
            o1 += head_s[br][k] * Wo[k * DD + lane + 64];
        }
        atomicAdd(&out[br * BB * DD + b * DD + lane], o0);
        atomicAdd(&out[br * BB * DD + b * DD + lane + 64], o1);
    }
}

// ---------------- finalize: divide by softmax denominator
__global__ void finalize_kernel(float* __restrict__ out, const float* __restrict__ s_ws) {
    int idx = blockIdx.x * blockDim.x + threadIdx.x;  // 16384 threads
    int br = idx / (BB * DD);
    int b  = (idx / DD) % BB;
    float s = s_ws[b * 2 + br];
    float v = out[idx];
    out[idx] = (s > 0.0f) ? v / s : 0.0f;
}

extern "C" void kernel_launch(void* const* d_in, const int* in_sizes, int n_in,
                              void* d_out, int out_size, void* d_ws, size_t ws_size,
                              hipStream_t stream) {
    const float* h     = (const float*)d_in[0];
    const float* adj   = (const float*)d_in[1];
    const int*   phone = (const int*)d_in[2];
    const float* Wq_bf = (const float*)d_in[3];
    const float* Wk_bf = (const float*)d_in[4];
    const float* Wv_bf = (const float*)d_in[5];
    const float* Wo_bf = (const float*)d_in[6];
    const float* Wq_af = (const float*)d_in[7];
    const float* Wk_af = (const float*)d_in[8];
    const float* Wv_af = (const float*)d_in[9];
    const float* Wo_af = (const float*)d_in[10];

    float* out  = (float*)d_out;
    float* s_ws = (float*)d_ws;   // 2*B floats = 512 B

    zero_kernel<<<64, 256, 0, stream>>>(out, s_ws);
    attn_partial<<<BB * CH, 64, 0, stream>>>(h, adj, phone,
                                             Wq_bf, Wk_bf, Wv_bf, Wo_bf,
                                             Wq_af, Wk_af, Wv_af, Wo_af,
                                             out, s_ws);
    finalize_kernel<<<64, 256, 0, stream>>>(out, s_ws);
}

// Round 2
// 80.593 us; speedup vs baseline: 1.3640x; 1.3640x over previous
//
#include <hip/hip_runtime.h>
#include <math.h>

#define BB 64
#define NN 2048
#define DD 128
#define KD 16
#define NORMF 0.25f
#define CHUNK 32
#define CH (NN / CHUNK)   // 64 chunks per batch

// ws layout (floats):
//   [0, 16384)        hagg[b][br][d]   (atomic accumulated)
//   [16384, 16512)    s[b][br]         (atomic accumulated)
//   [16512, 32896)    w[b][br][d]      (written by precompute)
#define WS_HAGG 0
#define WS_S    (BB * 2 * DD)
#define WS_W    (WS_S + BB * 2)
#define WS_TOT  (WS_W + BB * 2 * DD)

// ---------------- zero the accumulated regions of ws
__global__ void zero_kernel(float* __restrict__ ws) {
    int idx = blockIdx.x * blockDim.x + threadIdx.x;
    if (idx < WS_W) ws[idx] = 0.0f;
}

// ---------------- per-(b,branch): w[d] = NORM * sum_k Wk[d,k] * (h_phone @ Wq)[k]
__global__ void precompute_w(const float* __restrict__ h, const int* __restrict__ phone,
                             const float* __restrict__ Wq_bf, const float* __restrict__ Wk_bf,
                             const float* __restrict__ Wq_af, const float* __restrict__ Wk_af,
                             float* __restrict__ ws) {
    const int b = blockIdx.x;
    const int lane = threadIdx.x;
    __shared__ float hp[DD];
    __shared__ float q[2][KD];

    const float* hb = h + ((size_t)b * NN + phone[b]) * DD;
    float2 v = *(const float2*)(hb + 2 * lane);
    hp[2 * lane] = v.x;
    hp[2 * lane + 1] = v.y;
    __syncthreads();

    if (lane < 32) {
        int br = lane >> 4, k = lane & 15;
        const float* Wq = br ? Wq_af : Wq_bf;
        float acc = 0.0f;
        #pragma unroll 4
        for (int d = 0; d < DD; ++d) acc += hp[d] * Wq[d * KD + k];
        q[br][k] = acc;
    }
    __syncthreads();

    #pragma unroll
    for (int br = 0; br < 2; ++br) {
        const float* Wk = br ? Wk_af : Wk_bf;
        float a0 = 0.0f, a1 = 0.0f;
        #pragma unroll
        for (int k = 0; k < KD; ++k) {
            a0 += Wk[lane * KD + k] * q[br][k];
            a1 += Wk[(lane + 64) * KD + k] * q[br][k];
        }
        float* wp = ws + WS_W + ((size_t)b * 2 + br) * DD;
        wp[lane]      = NORMF * a0;
        wp[lane + 64] = NORMF * a1;
    }
}

// ---------------- main kernel: one wave per (b, 32-row chunk)
__launch_bounds__(64)
__global__ void attn_partial(const float* __restrict__ h,
                             const float* __restrict__ adj,
                             const int*   __restrict__ phone,
                             float* __restrict__ ws)
{
    const int blk  = blockIdx.x;
    const int b    = blk / CH;
    const int ch   = blk % CH;
    const int lane = threadIdx.x;
    const int half = lane >> 5;
    const int l    = lane & 31;
    const int dbase = 4 * l;
    const int ph   = phone[b];
    const int n0   = ch * CHUNK;

    __shared__ float part[CHUNK][33];  // partial dots, padded: conflict-free
    __shared__ float ea_s[CHUNK];

    // ---- issue all global loads up front (w, adj, 16 h-rows)
    const float* wp = ws + WS_W + (size_t)b * 2 * DD;
    const float4 wbf = *(const float4*)(wp + dbase);
    const float4 waf = *(const float4*)(wp + DD + dbase);

    const float adjv = adj[((size_t)b * NN + ph) * NN + n0 + l];  // halves duplicate

    const float* hb = h + (size_t)b * NN * DD;
    float4 hv[16];
    #pragma unroll
    for (int t = 0; t < 16; ++t) {
        const int r = 2 * t + half;
        hv[t] = *(const float4*)(hb + (size_t)(n0 + r) * DD + dbase);
    }

    // ---- phase A: per-lane partial dot for each row -> LDS transpose
    #pragma unroll
    for (int t = 0; t < 16; ++t) {
        const int r = 2 * t + half;
        const bool af = (n0 + r) >= ph;
        const float4 w = af ? waf : wbf;
        part[r][l] = hv[t].x * w.x + hv[t].y * w.y + hv[t].z * w.z + hv[t].w * w.w;
    }
    __syncthreads();

    // ---- phase B: one row per lane (halves duplicate rows 0..31)
    float a0 = 0.0f, a1 = 0.0f, a2 = 0.0f, a3 = 0.0f;
    #pragma unroll
    for (int j = 0; j < 32; j += 4) {
        a0 += part[l][j];
        a1 += part[l][j + 1];
        a2 += part[l][j + 2];
        a3 += part[l][j + 3];
    }
    const float p = (a0 + a1) + (a2 + a3);
    const float compat = 10.0f * tanhf(p);
    const float e = __expf(compat - 10.0f);       // fixed max: compat in (-10,10)
    const bool rowaf = (n0 + l) >= ph;
    const float es = (adjv != 0.0f) ? e : 0.0f;
    const float ea = es * adjv;

    if (lane < 32) ea_s[l] = ea;

    // ---- branch-masked butterfly over 32 rows (both halves identical)
    float sbf = rowaf ? 0.0f : es;
    float saf = rowaf ? es : 0.0f;
    #pragma unroll
    for (int m = 1; m <= 16; m <<= 1) {
        sbf += __shfl_xor(sbf, m, 64);
        saf += __shfl_xor(saf, m, 64);
    }
    if (lane == 0) {
        atomicAdd(&ws[WS_S + b * 2 + 0], sbf);
        atomicAdd(&ws[WS_S + b * 2 + 1], saf);
    }
    __syncthreads();

    // ---- phase C: weighted accumulation, h-tile reused from registers
    float hgbf[4] = {0, 0, 0, 0}, hgaf[4] = {0, 0, 0, 0};
    #pragma unroll
    for (int t = 0; t < 16; ++t) {
        const int r = 2 * t + half;
        const float ea_r = ea_s[r];                // broadcast read
        const bool af = (n0 + r) >= ph;
        const float eb = af ? 0.0f : ea_r;
        const float ef = af ? ea_r : 0.0f;
        hgbf[0] += eb * hv[t].x; hgbf[1] += eb * hv[t].y;
        hgbf[2] += eb * hv[t].z; hgbf[3] += eb * hv[t].w;
        hgaf[0] += ef * hv[t].x; hgaf[1] += ef * hv[t].y;
        hgaf[2] += ef * hv[t].z; hgaf[3] += ef * hv[t].w;
    }

    // combine halves (same d-range, different rows)
    #pragma unroll
    for (int i = 0; i < 4; ++i) {
        hgbf[i] += __shfl_xor(hgbf[i], 32, 64);
        hgaf[i] += __shfl_xor(hgaf[i], 32, 64);
    }
    if (lane < 32) {
        float* hg = ws + WS_HAGG + (size_t)b * 2 * DD;
        #pragma unroll
        for (int i = 0; i < 4; ++i) {
            atomicAdd(&hg[dbase + i], hgbf[i]);
            atomicAdd(&hg[DD + dbase + i], hgaf[i]);
        }
    }
}

// ---------------- finalize: head = hagg@Wv, out = (head@Wo)/s
__global__ void finalize_kernel(const float* __restrict__ Wv_bf, const float* __restrict__ Wo_bf,
                                const float* __restrict__ Wv_af, const float* __restrict__ Wo_af,
                                const float* __restrict__ ws, float* __restrict__ out) {
    const int b = blockIdx.x;
    const int lane = threadIdx.x;
    __shared__ float head[2][KD];

    const float* hg = ws + WS_HAGG + (size_t)b * 2 * DD;
    if (lane < 32) {
        int br = lane >> 4, k = lane & 15;
        const float* Wv = br ? Wv_af : Wv_bf;
        float acc = 0.0f;
        #pragma unroll 4
        for (int d = 0; d < DD; ++d) acc += hg[br * DD + d] * Wv[d * KD + k];
        head[br][k] = acc;
    }
    __syncthreads();

    #pragma unroll
    for (int br = 0; br < 2; ++br) {
        const float s = ws[WS_S + b * 2 + br];
        const float inv = (s > 0.0f) ? 1.0f / s : 0.0f;
        const float* Wo = br ? Wo_af : Wo_bf;
        float o0 = 0.0f, o1 = 0.0f;
        #pragma unroll
        for (int k = 0; k < KD; ++k) {
            o0 += head[br][k] * Wo[k * DD + lane];
            o1 += head[br][k] * Wo[k * DD + lane + 64];
        }
        out[br * BB * DD + b * DD + lane]      = o0 * inv;
        out[br * BB * DD + b * DD + lane + 64] = o1 * inv;
    }
}

extern "C" void kernel_launch(void* const* d_in, const int* in_sizes, int n_in,
                              void* d_out, int out_size, void* d_ws, size_t ws_size,
                              hipStream_t stream) {
    const float* h     = (const float*)d_in[0];
    const float* adj   = (const float*)d_in[1];
    const int*   phone = (const int*)d_in[2];
    const float* Wq_bf = (const float*)d_in[3];
    const float* Wk_bf = (const float*)d_in[4];
    const float* Wv_bf = (const float*)d_in[5];
    const float* Wo_bf = (const float*)d_in[6];
    const float* Wq_af = (const float*)d_in[7];
    const float* Wk_af = (const float*)d_in[8];
    const float* Wv_af = (const float*)d_in[9];
    const float* Wo_af = (const float*)d_in[10];

    float* out = (float*)d_out;
    float* ws  = (float*)d_ws;   // WS_TOT floats = ~131.6 KB

    zero_kernel<<<(WS_W + 255) / 256, 256, 0, stream>>>(ws);
    precompute_w<<<BB, 64, 0, stream>>>(h, phone, Wq_bf, Wk_bf, Wq_af, Wk_af, ws);
    attn_partial<<<BB * CH, 64, 0, stream>>>(h, adj, phone, ws);
    finalize_kernel<<<BB, 64, 0, stream>>>(Wv_bf, Wo_bf, Wv_af, Wo_af, ws, out);
}

// Round 3
// 59.947 us; speedup vs baseline: 1.8338x; 1.3444x over previous
//
#include <hip/hip_runtime.h>
#include <math.h>

#define BB 64
#define NN 2048
#define DD 128
#define KD 16
#define NORMF 0.25f
#define CHUNK 32
#define CH (NN / CHUNK)   // 64 chunks per batch
#define WAVES 4

// ws layout (floats):
//   [0, 16384)        hagg[b][br][d]   (atomic accumulated)
//   [16384, 16512)    s[b][br]         (atomic accumulated)
//   [16512, 32896)    w[b][br][d]      (written by setup)
#define WS_HAGG 0
#define WS_S    (BB * 2 * DD)
#define WS_W    (WS_S + BB * 2)
#define WS_TOT  (WS_W + BB * 2 * DD)

// ---------------- setup: zero accumulators for b + precompute w[b][br][d]
__global__ __launch_bounds__(64)
void setup_kernel(const float* __restrict__ h, const int* __restrict__ phone,
                  const float* __restrict__ Wq_bf, const float* __restrict__ Wk_bf,
                  const float* __restrict__ Wq_af, const float* __restrict__ Wk_af,
                  float* __restrict__ ws) {
    const int b = blockIdx.x;
    const int lane = threadIdx.x;
    __shared__ float hp[DD];
    __shared__ float q[2][KD];

    // zero this batch's accumulators (256 floats hagg + 2 floats s)
    float4 z = make_float4(0.f, 0.f, 0.f, 0.f);
    ((float4*)(ws + WS_HAGG + (size_t)b * 2 * DD))[lane] = z;
    if (lane < 2) ws[WS_S + b * 2 + lane] = 0.f;

    const float* hb = h + ((size_t)b * NN + phone[b]) * DD;
    float2 v = *(const float2*)(hb + 2 * lane);
    hp[2 * lane] = v.x;
    hp[2 * lane + 1] = v.y;
    __syncthreads();

    if (lane < 32) {
        int br = lane >> 4, k = lane & 15;
        const float* Wq = br ? Wq_af : Wq_bf;
        float acc = 0.0f;
        #pragma unroll 32
        for (int d = 0; d < DD; ++d) acc += hp[d] * Wq[d * KD + k];
        q[br][k] = acc;
    }
    __syncthreads();

    #pragma unroll
    for (int br = 0; br < 2; ++br) {
        const float* Wk = br ? Wk_af : Wk_bf;
        float a0 = 0.0f, a1 = 0.0f;
        #pragma unroll
        for (int k = 0; k < KD; ++k) {
            a0 += Wk[lane * KD + k] * q[br][k];
            a1 += Wk[(lane + 64) * KD + k] * q[br][k];
        }
        float* wp = ws + WS_W + ((size_t)b * 2) * DD;
        wp[lane]           = NORMF * a0;
        wp[lane + 64]      = NORMF * a1 * 0.f + NORMF * a1;  // keep simple write
    }
    // note: the above wrote br-interleaved wrong if left as-is; rewrite cleanly below
}

// (clean version of the w-write is inside setup_kernel2 — see below)

// ---------------- main kernel: 4 independent waves per block, 1 chunk each
__global__ __launch_bounds__(256)
void attn_partial(const float* __restrict__ h,
                  const float* __restrict__ adj,
                  const int*   __restrict__ phone,
                  float* __restrict__ ws)
{
    const int tid  = threadIdx.x;
    const int wid  = tid >> 6;
    const int lane = tid & 63;
    const int half = lane >> 5;
    const int l    = lane & 31;
    const int dbase = 4 * l;
    const int b    = blockIdx.x >> 4;                 // 16 blocks per batch
    const int ch   = ((blockIdx.x & 15) << 2) | wid;  // 64 chunks per batch
    const int n0   = ch * CHUNK;
    const int ph   = phone[b];

    __shared__ float part[WAVES][CHUNK][33];
    __shared__ float ea_s[WAVES][CHUNK];

    const float* wp = ws + WS_W + (size_t)b * 2 * DD;
    const float4 wbf = *(const float4*)(wp + dbase);
    const float4 waf = *(const float4*)(wp + DD + dbase);

    const float adjv = adj[((size_t)b * NN + ph) * NN + n0 + l];  // halves duplicate
    const unsigned long long mask = __ballot(adjv != 0.0f);       // bits 0..31 = rows

    const float* hb = h + (size_t)b * NN * DD;
    float4 hv[16];
    #pragma unroll
    for (int t = 0; t < 16; ++t) {
        hv[t] = make_float4(0.f, 0.f, 0.f, 0.f);
        const int r = 2 * t + half;
        if ((mask >> r) & 1ull)
            hv[t] = *(const float4*)(hb + (size_t)(n0 + r) * DD + dbase);
    }

    // ---- phase A: per-lane partial dot -> LDS transpose (skipped rows -> 0)
    #pragma unroll
    for (int t = 0; t < 16; ++t) {
        const int r = 2 * t + half;
        const bool af = (n0 + r) >= ph;
        const float4 w = af ? waf : wbf;
        part[wid][r][l] = hv[t].x * w.x + hv[t].y * w.y + hv[t].z * w.z + hv[t].w * w.w;
    }
    __syncthreads();

    // ---- phase B: one row per lane (halves duplicate rows 0..31)
    float a0 = 0.f, a1 = 0.f, a2 = 0.f, a3 = 0.f;
    #pragma unroll
    for (int j = 0; j < 32; j += 4) {
        a0 += part[wid][l][j];
        a1 += part[wid][l][j + 1];
        a2 += part[wid][l][j + 2];
        a3 += part[wid][l][j + 3];
    }
    const float p = (a0 + a1) + (a2 + a3);
    const float compat = 10.0f * tanhf(p);
    const float e = __expf(compat - 10.0f);       // fixed max: compat in (-10,10)
    const bool rowaf = (n0 + l) >= ph;
    const float es = (adjv != 0.0f) ? e : 0.0f;
    const float ea = es * adjv;

    if (lane < 32) ea_s[wid][l] = ea;

    float sbf = rowaf ? 0.0f : es;
    float saf = rowaf ? es : 0.0f;
    #pragma unroll
    for (int m = 1; m <= 16; m <<= 1) {
        sbf += __shfl_xor(sbf, m, 64);
        saf += __shfl_xor(saf, m, 64);
    }
    if (lane == 0) {
        atomicAdd(&ws[WS_S + b * 2 + 0], sbf);
        atomicAdd(&ws[WS_S + b * 2 + 1], saf);
    }
    __syncthreads();

    // ---- phase C: weighted accumulation from registers
    float hgbf[4] = {0, 0, 0, 0}, hgaf[4] = {0, 0, 0, 0};
    #pragma unroll
    for (int t = 0; t < 16; ++t) {
        const int r = 2 * t + half;
        const float ea_r = ea_s[wid][r];           // broadcast read
        const bool af = (n0 + r) >= ph;
        const float eb = af ? 0.0f : ea_r;
        const float ef = af ? ea_r : 0.0f;
        hgbf[0] += eb * hv[t].x; hgbf[1] += eb * hv[t].y;
        hgbf[2] += eb * hv[t].z; hgbf[3] += eb * hv[t].w;
        hgaf[0] += ef * hv[t].x; hgaf[1] += ef * hv[t].y;
        hgaf[2] += ef * hv[t].z; hgaf[3] += ef * hv[t].w;
    }
    #pragma unroll
    for (int i = 0; i < 4; ++i) {
        hgbf[i] += __shfl_xor(hgbf[i], 32, 64);
        hgaf[i] += __shfl_xor(hgaf[i], 32, 64);
    }
    if (lane < 32) {
        float* hg = ws + WS_HAGG + (size_t)b * 2 * DD;
        #pragma unroll
        for (int i = 0; i < 4; ++i) {
            atomicAdd(&hg[dbase + i], hgbf[i]);
            atomicAdd(&hg[DD + dbase + i], hgaf[i]);
        }
    }
}

// ---------------- finalize: head = hagg@Wv, out = (head@Wo)/s
__global__ __launch_bounds__(64)
void finalize_kernel(const float* __restrict__ Wv_bf, const float* __restrict__ Wo_bf,
                     const float* __restrict__ Wv_af, const float* __restrict__ Wo_af,
                     const float* __restrict__ ws, float* __restrict__ out) {
    const int b = blockIdx.x;
    const int lane = threadIdx.x;
    __shared__ float head[2][KD];

    const float* hg = ws + WS_HAGG + (size_t)b * 2 * DD;
    if (lane < 32) {
        int br = lane >> 4, k = lane & 15;
        const float* Wv = br ? Wv_af : Wv_bf;
        float acc = 0.0f;
        #pragma unroll 32
        for (int d = 0; d < DD; ++d) acc += hg[br * DD + d] * Wv[d * KD + k];
        head[br][k] = acc;
    }
    __syncthreads();

    #pragma unroll
    for (int br = 0; br < 2; ++br) {
        const float s = ws[WS_S + b * 2 + br];
        const float inv = (s > 0.0f) ? 1.0f / s : 0.0f;
        const float* Wo = br ? Wo_af : Wo_bf;
        float o0 = 0.0f, o1 = 0.0f;
        #pragma unroll
        for (int k = 0; k < KD; ++k) {
            o0 += head[br][k] * Wo[k * DD + lane];
            o1 += head[br][k] * Wo[k * DD + lane + 64];
        }
        out[br * BB * DD + b * DD + lane]      = o0 * inv;
        out[br * BB * DD + b * DD + lane + 64] = o1 * inv;
    }
}

// clean setup (the one actually launched): zero + q + w, correct w layout
__global__ __launch_bounds__(64)
void setup_kernel2(const float* __restrict__ h, const int* __restrict__ phone,
                   const float* __restrict__ Wq_bf, const float* __restrict__ Wk_bf,
                   const float* __restrict__ Wq_af, const float* __restrict__ Wk_af,
                   float* __restrict__ ws) {
    const int b = blockIdx.x;
    const int lane = threadIdx.x;
    __shared__ float hp[DD];
    __shared__ float q[2][KD];

    float4 z = make_float4(0.f, 0.f, 0.f, 0.f);
    ((float4*)(ws + WS_HAGG + (size_t)b * 2 * DD))[lane] = z;
    if (lane < 2) ws[WS_S + b * 2 + lane] = 0.f;

    const float* hb = h + ((size_t)b * NN + phone[b]) * DD;
    float2 v = *(const float2*)(hb + 2 * lane);
    hp[2 * lane] = v.x;
    hp[2 * lane + 1] = v.y;
    __syncthreads();

    if (lane < 32) {
        int br = lane >> 4, k = lane & 15;
        const float* Wq = br ? Wq_af : Wq_bf;
        float acc = 0.0f;
        #pragma unroll 32
        for (int d = 0; d < DD; ++d) acc += hp[d] * Wq[d * KD + k];
        q[br][k] = acc;
    }
    __syncthreads();

    #pragma unroll
    for (int br = 0; br < 2; ++br) {
        const float* Wk = br ? Wk_af : Wk_bf;
        float a0 = 0.0f, a1 = 0.0f;
        #pragma unroll
        for (int k = 0; k < KD; ++k) {
            a0 += Wk[lane * KD + k] * q[br][k];
            a1 += Wk[(lane + 64) * KD + k] * q[br][k];
        }
        float* wp = ws + WS_W + ((size_t)b * 2 + br) * DD;
        wp[lane]      = NORMF * a0;
        wp[lane + 64] = NORMF * a1;
    }
}

extern "C" void kernel_launch(void* const* d_in, const int* in_sizes, int n_in,
                              void* d_out, int out_size, void* d_ws, size_t ws_size,
                              hipStream_t stream) {
    const float* h     = (const float*)d_in[0];
    const float* adj   = (const float*)d_in[1];
    const int*   phone = (const int*)d_in[2];
    const float* Wq_bf = (const float*)d_in[3];
    const float* Wk_bf = (const float*)d_in[4];
    const float* Wv_bf = (const float*)d_in[5];
    const float* Wo_bf = (const float*)d_in[6];
    const float* Wq_af = (const float*)d_in[7];
    const float* Wk_af = (const float*)d_in[8];
    const float* Wv_af = (const float*)d_in[9];
    const float* Wo_af = (const float*)d_in[10];

    float* out = (float*)d_out;
    float* ws  = (float*)d_ws;   // WS_TOT floats ≈ 131.6 KB

    setup_kernel2<<<BB, 64, 0, stream>>>(h, phone, Wq_bf, Wk_bf, Wq_af, Wk_af, ws);
    attn_partial<<<BB * CH / WAVES, 256, 0, stream>>>(h, adj, phone, ws);
    finalize_kernel<<<BB, 64, 0, stream>>>(Wv_bf, Wo_bf, Wv_af, Wo_af, ws, out);
}

// Round 4
// 26.879 us; speedup vs baseline: 4.0898x; 2.2302x over previous
//
#include <hip/hip_runtime.h>
#include <math.h>

#define BB 64
#define NN 2048
#define DD 128
#define KD 16
#define NORMF 0.25f
#define CHUNK 32
#define PSTRIDE 260   // per-block partial: 2*DD hagg + 2 s + 2 pad

// ---------------- fused kernel: w-precompute + masked attention partials
// grid = BB * P blocks, 256 threads (4 waves). Each wave handles K=16/P chunks.
__global__ __launch_bounds__(256)
void attn_fused(const float* __restrict__ h,
                const float* __restrict__ adj,
                const int*   __restrict__ phone,
                const float* __restrict__ Wq_bf, const float* __restrict__ Wk_bf,
                const float* __restrict__ Wq_af, const float* __restrict__ Wk_af,
                float* __restrict__ ws, int P, int K)
{
    const int tid  = threadIdx.x;
    const int wid  = tid >> 6;
    const int lane = tid & 63;
    const int half = lane >> 5;
    const int l    = lane & 31;
    const int dbase = 4 * l;
    const int b    = blockIdx.x / P;
    const int bip  = blockIdx.x - b * P;
    const int ph   = phone[b];

    __shared__ float hp[DD];
    __shared__ float qpart[32][8];
    __shared__ float q[2][KD];
    __shared__ float w_s[2][DD];
    __shared__ float part[4][CHUNK][33];
    __shared__ float ea_s[4][CHUNK];
    __shared__ float red_h[4][2][DD];
    __shared__ float red_s[4][2];

    const float* hb = h + (size_t)b * NN * DD;

    // ---- h_phone -> LDS (512B, coalesced)
    if (tid < DD) hp[tid] = hb[(size_t)ph * DD + tid];
    __syncthreads();

    // ---- q[br][k] partials: 8 threads per (br,k), 16-d slices
    {
        const int pair = tid >> 3, sub = tid & 7;
        const int br = pair >> 4, k = pair & 15;
        const float* Wq = br ? Wq_af : Wq_bf;
        float acc = 0.f;
        #pragma unroll
        for (int i = 0; i < 16; ++i) {
            const int d = sub * 16 + i;
            acc += hp[d] * Wq[d * KD + k];
        }
        qpart[pair][sub] = acc;
    }
    __syncthreads();
    if (tid < 32) {
        float acc = 0.f;
        #pragma unroll
        for (int i = 0; i < 8; ++i) acc += qpart[tid][i];
        q[tid >> 4][tid & 15] = acc;
    }
    __syncthreads();

    // ---- w[br][d] = NORM * Wk[d,:]·q[br]: one thread per (br,d)
    {
        const int br = tid >> 7, d = tid & 127;
        const float* Wk = br ? Wk_af : Wk_bf;
        float acc = 0.f;
        #pragma unroll
        for (int k = 0; k < KD; ++k) acc += Wk[d * KD + k] * q[br][k];
        w_s[br][d] = NORMF * acc;
    }
    __syncthreads();

    const float4 wbf = *(const float4*)(&w_s[0][dbase]);
    const float4 waf = *(const float4*)(&w_s[1][dbase]);

    const int chbase = (bip * 4 + wid) * K;
    const float* adjrow = adj + ((size_t)b * NN + ph) * NN;

    float sbf = 0.f, saf = 0.f;
    float hgbf[4] = {0, 0, 0, 0}, hgaf[4] = {0, 0, 0, 0};

    for (int c = 0; c < K; ++c) {
        const int n0 = (chbase + c) * CHUNK;
        const float adjv = adjrow[n0 + l];                 // halves duplicate rows
        const unsigned long long mask = __ballot(adjv != 0.f);  // bits 0..31 = rows

        float4 hv[16];
        #pragma unroll
        for (int t = 0; t < 16; ++t) {
            const int r = 2 * t + half;
            hv[t] = make_float4(0.f, 0.f, 0.f, 0.f);
            if ((mask >> r) & 1ull)
                hv[t] = *(const float4*)(hb + (size_t)(n0 + r) * DD + dbase);
        }

        // phase A: per-lane partial dots -> LDS transpose
        #pragma unroll
        for (int t = 0; t < 16; ++t) {
            const int r = 2 * t + half;
            const float4 w = ((n0 + r) >= ph) ? waf : wbf;
            part[wid][r][l] = hv[t].x * w.x + hv[t].y * w.y + hv[t].z * w.z + hv[t].w * w.w;
        }
        __syncthreads();

        // phase B: one row per lane (halves duplicate)
        float a0 = 0.f, a1 = 0.f, a2 = 0.f, a3 = 0.f;
        #pragma unroll
        for (int j = 0; j < 32; j += 4) {
            a0 += part[wid][l][j];
            a1 += part[wid][l][j + 1];
            a2 += part[wid][l][j + 2];
            a3 += part[wid][l][j + 3];
        }
        const float p = (a0 + a1) + (a2 + a3);
        const float e = __expf(10.f * tanhf(p) - 10.f);    // fixed max: compat in (-10,10)
        const float es = (adjv != 0.f) ? e : 0.f;
        const float ea = es * adjv;
        const bool rowaf = (n0 + l) >= ph;
        sbf += rowaf ? 0.f : es;       // lane-private accumulation across chunks
        saf += rowaf ? es : 0.f;
        if (lane < 32) ea_s[wid][l] = ea;
        __syncthreads();

        // phase C: weighted accumulation from registers
        #pragma unroll
        for (int t = 0; t < 16; ++t) {
            const int r = 2 * t + half;
            const float ear = ea_s[wid][r];                // broadcast read
            const bool af = (n0 + r) >= ph;
            const float eb = af ? 0.f : ear;
            const float ef = af ? ear : 0.f;
            hgbf[0] += eb * hv[t].x; hgbf[1] += eb * hv[t].y;
            hgbf[2] += eb * hv[t].z; hgbf[3] += eb * hv[t].w;
            hgaf[0] += ef * hv[t].x; hgaf[1] += ef * hv[t].y;
            hgaf[2] += ef * hv[t].z; hgaf[3] += ef * hv[t].w;
        }
    }

    // ---- per-wave reductions (once, after all chunks)
    #pragma unroll
    for (int m = 1; m <= 16; m <<= 1) {
        sbf += __shfl_xor(sbf, m, 64);   // sums lanes 0..31 contributions
        saf += __shfl_xor(saf, m, 64);
    }
    #pragma unroll
    for (int i = 0; i < 4; ++i) {
        hgbf[i] += __shfl_xor(hgbf[i], 32, 64);   // combine halves (same d-range)
        hgaf[i] += __shfl_xor(hgaf[i], 32, 64);
    }
    if (lane < 32) {
        #pragma unroll
        for (int i = 0; i < 4; ++i) {
            red_h[wid][0][dbase + i] = hgbf[i];
            red_h[wid][1][dbase + i] = hgaf[i];
        }
    }
    if (lane == 0) { red_s[wid][0] = sbf; red_s[wid][1] = saf; }
    __syncthreads();

    // ---- block partial -> ws (no atomics, fully written, coalesced)
    {
        const int br = tid >> 7, d = tid & 127;
        float* op = ws + (size_t)blockIdx.x * PSTRIDE;
        op[br * DD + d] = red_h[0][br][d] + red_h[1][br][d] + red_h[2][br][d] + red_h[3][br][d];
        if (tid < 2)
            op[2 * DD + tid] = red_s[0][tid] + red_s[1][tid] + red_s[2][tid] + red_s[3][tid];
    }
}

// ---------------- finalize: reduce P partials, head = hagg@Wv, out = (head@Wo)/s
__global__ __launch_bounds__(256)
void finalize_kernel(const float* __restrict__ Wv_bf, const float* __restrict__ Wo_bf,
                     const float* __restrict__ Wv_af, const float* __restrict__ Wo_af,
                     const float* __restrict__ ws, float* __restrict__ out, int P)
{
    const int b = blockIdx.x;
    const int tid = threadIdx.x;
    __shared__ float hs[2][DD];
    __shared__ float ssum[2];
    __shared__ float hpart[32][8];
    __shared__ float head[2][KD];

    const float* base = ws + (size_t)b * P * PSTRIDE;
    {
        const int br = tid >> 7, d = tid & 127;
        float acc = 0.f;
        for (int p = 0; p < P; ++p) acc += base[(size_t)p * PSTRIDE + br * DD + d];
        hs[br][d] = acc;
    }
    if (tid < 2) {
        float acc = 0.f;
        for (int p = 0; p < P; ++p) acc += base[(size_t)p * PSTRIDE + 2 * DD + tid];
        ssum[tid] = acc;
    }
    __syncthreads();

    // head[br][k] partials: 8 threads per (br,k)
    {
        const int pair = tid >> 3, sub = tid & 7;
        const int br = pair >> 4, k = pair & 15;
        const float* Wv = br ? Wv_af : Wv_bf;
        float acc = 0.f;
        #pragma unroll
        for (int i = 0; i < 16; ++i) {
            const int d = sub * 16 + i;
            acc += hs[br][d] * Wv[d * KD + k];
        }
        hpart[pair][sub] = acc;
    }
    __syncthreads();
    if (tid < 32) {
        float acc = 0.f;
        #pragma unroll
        for (int i = 0; i < 8; ++i) acc += hpart[tid][i];
        head[tid >> 4][tid & 15] = acc;
    }
    __syncthreads();

    {
        const int br = tid >> 7, j = tid & 127;
        const float s = ssum[br];
        const float inv = (s > 0.f) ? 1.f / s : 0.f;
        const float* Wo = br ? Wo_af : Wo_bf;
        float acc = 0.f;
        #pragma unroll
        for (int k = 0; k < KD; ++k) acc += head[br][k] * Wo[k * DD + j];
        out[br * BB * DD + b * DD + j] = acc * inv;
    }
}

extern "C" void kernel_launch(void* const* d_in, const int* in_sizes, int n_in,
                              void* d_out, int out_size, void* d_ws, size_t ws_size,
                              hipStream_t stream) {
    const float* h     = (const float*)d_in[0];
    const float* adj   = (const float*)d_in[1];
    const int*   phone = (const int*)d_in[2];
    const float* Wq_bf = (const float*)d_in[3];
    const float* Wk_bf = (const float*)d_in[4];
    const float* Wv_bf = (const float*)d_in[5];
    const float* Wo_bf = (const float*)d_in[6];
    const float* Wq_af = (const float*)d_in[7];
    const float* Wk_af = (const float*)d_in[8];
    const float* Wv_af = (const float*)d_in[9];
    const float* Wo_af = (const float*)d_in[10];

    float* out = (float*)d_out;
    float* ws  = (float*)d_ws;

    // blocks per batch P in {16,8,4,2,1}, max fitting ws (P=16 needs ~1.04 MB)
    int P = 16;
    while ((size_t)(BB * P * PSTRIDE) * sizeof(float) > ws_size && P > 1) P >>= 1;
    const int K = 16 / P;   // chunks per wave

    attn_fused<<<BB * P, 256, 0, stream>>>(h, adj, phone,
                                           Wq_bf, Wk_bf, Wq_af, Wk_af, ws, P, K);
    finalize_kernel<<<BB, 256, 0, stream>>>(Wv_bf, Wo_bf, Wv_af, Wo_af, ws, out, P);
}

// Round 5
// 20.492 us; speedup vs baseline: 5.3646x; 1.3117x over previous
//
#include <hip/hip_runtime.h>
#include <math.h>

#define BB 64
#define NN 2048
#define DD 128
#define KD 16
#define NORMF 0.25f
#define CHUNK 32
#define PSTRIDE 260                 // per-block partial: 2*DD + 2 + pad
#define WS_PART (BB * 2 * DD)       // floats; w[b][br][d] lives in ws[0, WS_PART)

// wave-local LDS fence: DS ops within a wave are in-order; we only need the
// writes drained before cross-LANE reads. No __syncthreads (data is wave-private).
__device__ __forceinline__ void wave_lds_fence() {
    asm volatile("s_waitcnt lgkmcnt(0)" ::: "memory");
    __builtin_amdgcn_wave_barrier();
}

// ---------------- setup: w[b][br][d] = NORM * Wk[d,:]·(h_phone @ Wq) ----------------
__global__ __launch_bounds__(256)
void setup_w(const float* __restrict__ h, const int* __restrict__ phone,
             const float* __restrict__ Wq_bf, const float* __restrict__ Wk_bf,
             const float* __restrict__ Wq_af, const float* __restrict__ Wk_af,
             float* __restrict__ ws)
{
    const int b = blockIdx.x;
    const int tid = threadIdx.x;
    __shared__ float hp[DD];
    __shared__ float qpart[32][8];
    __shared__ float q[2][KD];

    if (tid < DD) hp[tid] = h[((size_t)b * NN + phone[b]) * DD + tid];
    __syncthreads();

    {   // q partials: 8 threads per (br,k)
        const int pair = tid >> 3, sub = tid & 7;
        const int br = pair >> 4, k = pair & 15;
        const float* Wq = br ? Wq_af : Wq_bf;
        float acc = 0.f;
        #pragma unroll
        for (int i = 0; i < 16; ++i) {
            const int d = sub * 16 + i;
            acc += hp[d] * Wq[d * KD + k];
        }
        qpart[pair][sub] = acc;
    }
    __syncthreads();
    if (tid < 32) {
        float acc = 0.f;
        #pragma unroll
        for (int i = 0; i < 8; ++i) acc += qpart[tid][i];
        q[tid >> 4][tid & 15] = acc;
    }
    __syncthreads();

    {   // w: one thread per (br,d)
        const int br = tid >> 7, d = tid & 127;
        const float* Wk = br ? Wk_af : Wk_bf;
        float acc = 0.f;
        #pragma unroll
        for (int k = 0; k < KD; ++k) acc += Wk[d * KD + k] * q[br][k];
        ws[((size_t)b * 2 + br) * DD + d] = NORMF * acc;
    }
}

// ---------------- main: masked streaming over h, block partials -> ws ----------------
template <int P>
__global__ __launch_bounds__(256)
void attn_main(const float* __restrict__ h,
               const float* __restrict__ adj,
               const int*   __restrict__ phone,
               float* __restrict__ ws)
{
    constexpr int K = 16 / P;          // chunks per wave
    const int tid  = threadIdx.x;
    const int wid  = tid >> 6;
    const int lane = tid & 63;
    const int half = lane >> 5;
    const int l    = lane & 31;
    const int dbase = 4 * l;

    // XCD swizzle: keep all blocks of a batch on one XCD (adj row + w L2 reuse)
    const int xcd  = blockIdx.x & 7;
    const int slot = blockIdx.x >> 3;
    const int b    = xcd + 8 * (slot / P);
    const int bip  = slot % P;
    const int ph   = phone[b];

    __shared__ float part[4][CHUNK][33];
    __shared__ float ea_s[4][CHUNK];
    __shared__ float red_h[4][2][DD];
    __shared__ float red_s[4][2];

    const float* adjrow = adj + ((size_t)b * NN + ph) * NN;
    const float* hb     = h + (size_t)b * NN * DD;
    const int chbase    = (bip * 4 + wid) * K;

    // issue adj loads first (HBM latency hides the w loads + setup below)
    float adjv[K];
    #pragma unroll
    for (int c = 0; c < K; ++c) adjv[c] = adjrow[(chbase + c) * CHUNK + l];

    // w vectors (L2-hot, written by setup_w)
    const float* wp = ws + (size_t)b * 2 * DD;
    const float4 wbf = *(const float4*)(wp + dbase);
    const float4 waf = *(const float4*)(wp + DD + dbase);

    float sbf = 0.f, saf = 0.f;
    float hgbf[4] = {0, 0, 0, 0}, hgaf[4] = {0, 0, 0, 0};

    #pragma unroll
    for (int c = 0; c < K; ++c) {
        const int n0 = (chbase + c) * CHUNK;
        const unsigned long long mask = __ballot(adjv[c] != 0.f);  // bits 0..31 = rows

        float4 hv[16];
        #pragma unroll
        for (int t = 0; t < 16; ++t) {
            const int r = 2 * t + half;
            hv[t] = make_float4(0.f, 0.f, 0.f, 0.f);
            if ((mask >> r) & 1ull)
                hv[t] = *(const float4*)(hb + (size_t)(n0 + r) * DD + dbase);
        }

        // phase A: per-lane partial dots -> LDS transpose (wave-private)
        #pragma unroll
        for (int t = 0; t < 16; ++t) {
            const int r = 2 * t + half;
            const float4 w = ((n0 + r) >= ph) ? waf : wbf;
            part[wid][r][l] = hv[t].x * w.x + hv[t].y * w.y + hv[t].z * w.z + hv[t].w * w.w;
        }
        wave_lds_fence();

        // phase B: one row per lane (halves duplicate rows 0..31)
        float a0 = 0.f, a1 = 0.f, a2 = 0.f, a3 = 0.f;
        #pragma unroll
        for (int j = 0; j < 32; j += 4) {
            a0 += part[wid][l][j];
            a1 += part[wid][l][j + 1];
            a2 += part[wid][l][j + 2];
            a3 += part[wid][l][j + 3];
        }
        const float p = (a0 + a1) + (a2 + a3);
        const float e = __expf(10.f * tanhf(p) - 10.f);   // fixed max: compat in (-10,10)
        const float es = (adjv[c] != 0.f) ? e : 0.f;
        const float ea = es * adjv[c];
        const bool rowaf = (n0 + l) >= ph;
        sbf += rowaf ? 0.f : es;
        saf += rowaf ? es : 0.f;
        if (lane < 32) ea_s[wid][l] = ea;
        wave_lds_fence();

        // phase C: weighted accumulation from registers
        #pragma unroll
        for (int t = 0; t < 16; ++t) {
            const int r = 2 * t + half;
            const float ear = ea_s[wid][r];               // broadcast read
            const bool af = (n0 + r) >= ph;
            const float eb = af ? 0.f : ear;
            const float ef = af ? ear : 0.f;
            hgbf[0] += eb * hv[t].x; hgbf[1] += eb * hv[t].y;
            hgbf[2] += eb * hv[t].z; hgbf[3] += eb * hv[t].w;
            hgaf[0] += ef * hv[t].x; hgaf[1] += ef * hv[t].y;
            hgaf[2] += ef * hv[t].z; hgaf[3] += ef * hv[t].w;
        }
    }

    // per-wave reductions
    #pragma unroll
    for (int m = 1; m <= 16; m <<= 1) {
        sbf += __shfl_xor(sbf, m, 64);   // stays within 32-halves; halves duplicate
        saf += __shfl_xor(saf, m, 64);
    }
    #pragma unroll
    for (int i = 0; i < 4; ++i) {
        hgbf[i] += __shfl_xor(hgbf[i], 32, 64);   // combine halves (same d-range)
        hgaf[i] += __shfl_xor(hgaf[i], 32, 64);
    }
    if (lane < 32) {
        #pragma unroll
        for (int i = 0; i < 4; ++i) {
            red_h[wid][0][dbase + i] = hgbf[i];
            red_h[wid][1][dbase + i] = hgaf[i];
        }
    }
    if (lane == 0) { red_s[wid][0] = sbf; red_s[wid][1] = saf; }
    __syncthreads();   // the only cross-wave exchange

    {   // block partial -> ws (coalesced, no atomics)
        const int br = tid >> 7, d = tid & 127;
        float* op = ws + WS_PART + (size_t)(b * P + bip) * PSTRIDE;
        op[br * DD + d] = red_h[0][br][d] + red_h[1][br][d] + red_h[2][br][d] + red_h[3][br][d];
        if (tid < 2)
            op[2 * DD + tid] = red_s[0][tid] + red_s[1][tid] + red_s[2][tid] + red_s[3][tid];
    }
}

// ---------------- finalize: reduce P partials, head = hagg@Wv, out = (head@Wo)/s ----
template <int P>
__global__ __launch_bounds__(256)
void finalize_kernel(const float* __restrict__ Wv_bf, const float* __restrict__ Wo_bf,
                     const float* __restrict__ Wv_af, const float* __restrict__ Wo_af,
                     const float* __restrict__ ws, float* __restrict__ out)
{
    const int b = blockIdx.x;
    const int tid = threadIdx.x;
    __shared__ float hs[2][DD];
    __shared__ float ssum[2];
    __shared__ float hpart[32][8];
    __shared__ float head[2][KD];

    const float* base = ws + WS_PART + (size_t)b * P * PSTRIDE;
    {
        const int br = tid >> 7, d = tid & 127;
        float acc = 0.f;
        #pragma unroll
        for (int p = 0; p < P; ++p) acc += base[(size_t)p * PSTRIDE + br * DD + d];
        hs[br][d] = acc;
    }
    if (tid < 2) {
        float acc = 0.f;
        #pragma unroll
        for (int p = 0; p < P; ++p) acc += base[(size_t)p * PSTRIDE + 2 * DD + tid];
        ssum[tid] = acc;
    }
    __syncthreads();

    {   // head partials: 8 threads per (br,k)
        const int pair = tid >> 3, sub = tid & 7;
        const int br = pair >> 4, k = pair & 15;
        const float* Wv = br ? Wv_af : Wv_bf;
        float acc = 0.f;
        #pragma unroll
        for (int i = 0; i < 16; ++i) {
            const int d = sub * 16 + i;
            acc += hs[br][d] * Wv[d * KD + k];
        }
        hpart[pair][sub] = acc;
    }
    __syncthreads();
    if (tid < 32) {
        float acc = 0.f;
        #pragma unroll
        for (int i = 0; i < 8; ++i) acc += hpart[tid][i];
        head[tid >> 4][tid & 15] = acc;
    }
    __syncthreads();

    {
        const int br = tid >> 7, j = tid & 127;
        const float s = ssum[br];
        const float inv = (s > 0.f) ? 1.f / s : 0.f;
        const float* Wo = br ? Wo_af : Wo_bf;
        float acc = 0.f;
        #pragma unroll
        for (int k = 0; k < KD; ++k) acc += head[br][k] * Wo[k * DD + j];
        out[br * BB * DD + b * DD + j] = acc * inv;
    }
}

extern "C" void kernel_launch(void* const* d_in, const int* in_sizes, int n_in,
                              void* d_out, int out_size, void* d_ws, size_t ws_size,
                              hipStream_t stream) {
    const float* h     = (const float*)d_in[0];
    const float* adj   = (const float*)d_in[1];
    const int*   phone = (const int*)d_in[2];
    const float* Wq_bf = (const float*)d_in[3];
    const float* Wk_bf = (const float*)d_in[4];
    const float* Wv_bf = (const float*)d_in[5];
    const float* Wo_bf = (const float*)d_in[6];
    const float* Wq_af = (const float*)d_in[7];
    const float* Wk_af = (const float*)d_in[8];
    const float* Wv_af = (const float*)d_in[9];
    const float* Wo_af = (const float*)d_in[10];

    float* out = (float*)d_out;
    float* ws  = (float*)d_ws;

    // pick the largest compile-time P whose partial region fits ws
    int P = 16;
    while (P > 1 && (size_t)(WS_PART + (size_t)BB * P * PSTRIDE) * sizeof(float) > ws_size)
        P >>= 1;

    setup_w<<<BB, 256, 0, stream>>>(h, phone, Wq_bf, Wk_bf, Wq_af, Wk_af, ws);

    switch (P) {
    case 16:
        attn_main<16><<<BB * 16, 256, 0, stream>>>(h, adj, phone, ws);
        finalize_kernel<16><<<BB, 256, 0, stream>>>(Wv_bf, Wo_bf, Wv_af, Wo_af, ws, out);
        break;
    case 8:
        attn_main<8><<<BB * 8, 256, 0, stream>>>(h, adj, phone, ws);
        finalize_kernel<8><<<BB, 256, 0, stream>>>(Wv_bf, Wo_bf, Wv_af, Wo_af, ws, out);
        break;
    case 4:
        attn_main<4><<<BB * 4, 256, 0, stream>>>(h, adj, phone, ws);
        finalize_kernel<4><<<BB, 256, 0, stream>>>(Wv_bf, Wo_bf, Wv_af, Wo_af, ws, out);
        break;
    case 2:
        attn_main<2><<<BB * 2, 256, 0, stream>>>(h, adj, phone, ws);
        finalize_kernel<2><<<BB, 256, 0, stream>>>(Wv_bf, Wo_bf, Wv_af, Wo_af, ws, out);
        break;
    default:
        attn_main<1><<<BB, 256, 0, stream>>>(h, adj, phone, ws);
        finalize_kernel<1><<<BB, 256, 0, stream>>>(Wv_bf, Wo_bf, Wv_af, Wo_af, ws, out);
        break;
    }
}